// Round 11
// baseline (182.989 us; speedup 1.0000x reference)
//
#include <hip/hip_runtime.h>

typedef __attribute__((ext_vector_type(8))) short bf16x8;
typedef __attribute__((ext_vector_type(4))) float f32x4;
typedef __attribute__((ext_vector_type(16))) float f32x16;

__device__ __forceinline__ ushort f2bf(float f) {
    union { float f; unsigned u; } x; x.f = f;
    unsigned r = x.u + 0x7fffu + ((x.u >> 16) & 1u);
    return (ushort)(r >> 16);
}

__device__ __forceinline__ void async16(const void* g, void* l) {
    __builtin_amdgcn_global_load_lds(
        (const __attribute__((address_space(1))) void*)g,
        (__attribute__((address_space(3))) void*)l, 16, 0, 0);
}

__device__ __forceinline__ f32x4 mfma16(bf16x8 a, bf16x8 b, f32x4 c) {
    return __builtin_amdgcn_mfma_f32_16x16x32_bf16(a, b, c, 0, 0, 0);
}
__device__ __forceinline__ f32x16 mfma32(bf16x8 a, bf16x8 b, f32x16 c) {
    return __builtin_amdgcn_mfma_f32_32x32x16_bf16(a, b, c, 0, 0, 0);
}

__device__ __forceinline__ f32x4 zero4() { f32x4 z = {0.f, 0.f, 0.f, 0.f}; return z; }

// cross-half (lane vs lane^32) reduce — VERIFIED shfl_xor form (R3-R5/R8).
// NOTE: inline-asm v_permlane32_swap_b32 failed correctness in both operand
// orders (R6/R7, absmax ~4) — do not reintroduce.
__device__ __forceinline__ float xhalf_max(float v) {
    return fmaxf(v, __shfl_xor(v, 32));
}
__device__ __forceinline__ float xhalf_sum(float v) {
    return v + __shfl_xor(v, 32);
}

#define PIPE_BARRIER(cond_more)                                          \
    do {                                                                 \
        if (cond_more) asm volatile("s_waitcnt vmcnt(4)" ::: "memory");  \
        else           asm volatile("s_waitcnt vmcnt(0)" ::: "memory");  \
        asm volatile("s_waitcnt lgkmcnt(0)" ::: "memory");               \
        __builtin_amdgcn_sched_barrier(0);                               \
        __builtin_amdgcn_s_barrier();                                    \
        __builtin_amdgcn_sched_barrier(0);                               \
    } while (0)

#define END_BARRIER()                                                    \
    do {                                                                 \
        asm volatile("s_waitcnt lgkmcnt(0)" ::: "memory");               \
        __builtin_amdgcn_sched_barrier(0);                               \
        __builtin_amdgcn_s_barrier();                                    \
        __builtin_amdgcn_sched_barrier(0);                               \
    } while (0)

// -------- fused fp32 -> bf16 conversion for all 7 tensors, one launch --------
__global__ void cvt7_kernel(
    const float* __restrict__ s0, const float* __restrict__ s1, const float* __restrict__ s2,
    const float* __restrict__ s3, const float* __restrict__ s4, const float* __restrict__ s5,
    const float* __restrict__ s6,
    ushort* __restrict__ d0, ushort* __restrict__ d1, ushort* __restrict__ d2,
    ushort* __restrict__ d3, ushort* __restrict__ d4, ushort* __restrict__ d5,
    ushort* __restrict__ d6)
{
    int y = blockIdx.y;
    const float* s; ushort* d; int n4;
    if      (y == 0) { s = s0; d = d0; n4 = 1048576; }
    else if (y == 1) { s = s1; d = d1; n4 = 1048576; }
    else if (y == 2) { s = s2; d = d2; n4 = 1048576; }
    else if (y == 3) { s = s3; d = d3; n4 = 262144; }
    else if (y == 4) { s = s4; d = d4; n4 = 262144; }
    else if (y == 5) { s = s5; d = d5; n4 = 262144; }
    else             { s = s6; d = d6; n4 = 262144; }
    int i = blockIdx.x * 256 + threadIdx.x;
    if (i >= n4) return;
    float4 v = ((const float4*)s)[i];
    ushort4 o;
    o.x = f2bf(v.x); o.y = f2bf(v.y); o.z = f2bf(v.z); o.w = f2bf(v.w);
    ((ushort4*)d)[i] = o;
}

// -------- shared GEMM core: 128x128 tile, BK=32, 3-deep counted-vmcnt pipeline --------
template<bool SWAP>
__device__ __forceinline__ void gemm_core(
    const ushort* __restrict__ A, const ushort* __restrict__ W,
    char* smem, int bm, int bn, int tid, f32x4 acc[4][4])
{
    const int lane = tid & 63;
    const int wid  = tid >> 6;
    const int wr = wid >> 1, wc = wid & 1;
    const int l15 = lane & 15, g = lane >> 4;

    auto stage = [&](int kt) {
        char* As = smem + (kt % 3) * 16384;
        char* Bs = As + 8192;
        #pragma unroll
        for (int it = 0; it < 2; ++it) {
            int c = it * 256 + tid;
            int row = c >> 2, inner = c & 3;
            int srcoff = (inner ^ (row & 3)) * 16;
            async16((const char*)A + (size_t)(bm * 128 + row) * 2048 + kt * 64 + srcoff, As + c * 16);
            async16((const char*)W + (size_t)(bn * 128 + row) * 2048 + kt * 64 + srcoff, Bs + c * 16);
        }
    };

    stage(0);
    stage(1);

    for (int kt = 0; kt < 32; ++kt) {
        PIPE_BARRIER(kt < 31);
        if (kt < 30) stage(kt + 2);

        const char* As = smem + (kt % 3) * 16384;
        const char* Bs = As + 8192;
        bf16x8 af[4], bfr[4];
        #pragma unroll
        for (int mt = 0; mt < 4; ++mt) {
            int row = wr * 64 + mt * 16 + l15;
            af[mt] = *(const bf16x8*)(As + ((row * 64 + g * 16) ^ ((row & 3) << 4)));
        }
        #pragma unroll
        for (int nt = 0; nt < 4; ++nt) {
            int row = wc * 64 + nt * 16 + l15;
            bfr[nt] = *(const bf16x8*)(Bs + ((row * 64 + g * 16) ^ ((row & 3) << 4)));
        }
        __builtin_amdgcn_s_setprio(1);
        #pragma unroll
        for (int mt = 0; mt < 4; ++mt)
            #pragma unroll
            for (int nt = 0; nt < 4; ++nt) {
                if (SWAP) acc[mt][nt] = mfma16(bfr[nt], af[mt], acc[mt][nt]);
                else      acc[mt][nt] = mfma16(af[mt], bfr[nt], acc[mt][nt]);
            }
        __builtin_amdgcn_s_setprio(0);
    }
}

// -------- merged QKV projection: grid (96, 8), z = x%3 --------
// Q scaled by 0.125*log2(e) (exp2-domain softmax downstream).
__global__ __launch_bounds__(256, 2) void gemm_qkv(
    const ushort* __restrict__ Qb, const ushort* __restrict__ Kb, const ushort* __restrict__ Vb,
    const ushort* __restrict__ WQ, const ushort* __restrict__ WK, const ushort* __restrict__ WV,
    ushort* __restrict__ qhb, ushort* __restrict__ khb, ushort* __restrict__ vhT)
{
    __shared__ __align__(16) char smem[49152];
    const int tid = threadIdx.x;
    const int z  = blockIdx.x % 3;
    const int bm = blockIdx.x / 3;
    const int bn = blockIdx.y;
    const int lane = tid & 63;
    const int wid  = tid >> 6;
    const int wr = wid >> 1, wc = wid & 1;
    const int l15 = lane & 15, g = lane >> 4;

    const ushort* A  = (z == 0) ? Qb : (z == 1) ? Kb : Vb;
    const ushort* Wm = (z == 0) ? WQ : (z == 1) ? WK : WV;

    f32x4 acc[4][4];
    #pragma unroll
    for (int i = 0; i < 4; ++i)
        #pragma unroll
        for (int j = 0; j < 4; ++j) acc[i][j] = zero4();

    if (z == 2) {
        gemm_core<true>(A, Wm, smem, bm, bn, tid, acc);
        #pragma unroll
        for (int mt = 0; mt < 4; ++mt)
            #pragma unroll
            for (int nt = 0; nt < 4; ++nt)
                #pragma unroll
                for (int j = 0; j < 4; ++j) {
                    int n = bn * 128 + wc * 64 + nt * 16 + g * 4 + j;
                    int m = bm * 128 + wr * 64 + mt * 16 + l15;
                    int b = m >> 11, s = m & 2047, h = (n >> 6) & 15, d = n & 63;
                    vhT[(((size_t)(b * 16 + h)) * 64 + d) * 2048 + s] = f2bf(acc[mt][nt][j]);
                }
    } else {
        gemm_core<false>(A, Wm, smem, bm, bn, tid, acc);
        const float scale = (z == 0) ? 0.18033688011112042f : 1.0f;  // 0.125 * log2(e)
        ushort* outb = (z == 0) ? qhb : khb;
        #pragma unroll
        for (int mt = 0; mt < 4; ++mt)
            #pragma unroll
            for (int nt = 0; nt < 4; ++nt)
                #pragma unroll
                for (int j = 0; j < 4; ++j) {
                    int m = bm * 128 + wr * 64 + mt * 16 + g * 4 + j;
                    int n = bn * 128 + wc * 64 + nt * 16 + l15;
                    int b = m >> 11, s = m & 2047, h = n >> 6, d = n & 63;
                    outb[(((size_t)(b * 16 + h)) * 2048 + s) * 64 + d] = f2bf(acc[mt][nt][j] * scale);
                }
    }
}

// -------- final GEMM: out = A @ W^T + bias (fp32 out) --------
__global__ __launch_bounds__(256, 2) void gemm_fc(
    const ushort* __restrict__ A, const ushort* __restrict__ W,
    float* __restrict__ outf, const float* __restrict__ bias)
{
    __shared__ __align__(16) char smem[49152];
    const int tid = threadIdx.x;
    const int lane = tid & 63;
    const int wid  = tid >> 6;
    const int wr = wid >> 1, wc = wid & 1;
    const int l15 = lane & 15, g = lane >> 4;

    f32x4 acc[4][4];
    #pragma unroll
    for (int i = 0; i < 4; ++i)
        #pragma unroll
        for (int j = 0; j < 4; ++j) acc[i][j] = zero4();

    gemm_core<false>(A, W, smem, blockIdx.x, blockIdx.y, tid, acc);

    #pragma unroll
    for (int mt = 0; mt < 4; ++mt)
        #pragma unroll
        for (int nt = 0; nt < 4; ++nt)
            #pragma unroll
            for (int j = 0; j < 4; ++j) {
                int m = blockIdx.x * 128 + wr * 64 + mt * 16 + g * 4 + j;
                int n = blockIdx.y * 128 + wc * 64 + nt * 16 + l15;
                outf[(size_t)m * 1024 + n] = acc[mt][nt][j] + bias[n];
            }
}

// -------- causal flash attention --------
// grid 256 1-D, block 1024 = 16 waves = 4 waves/SIMD. XCD-aware decode.
// Block does q-tile pair {qx, 15-qx}. KV chunk 256/iter split 4-ways across
// wave-groups -> exactly 9 iters/block. 2-deep counted-vmcnt, 128KB LDS.
// R11: plain __launch_bounds__(1024) — R10's ",4" min-waves arg forced
// VGPR=64 and spilled (FETCH 178MB of scratch). Compiler caps at 128 here.
__global__ __launch_bounds__(1024) void attn_kernel(
    const ushort* __restrict__ qh, const ushort* __restrict__ kh,
    const ushort* __restrict__ vhT, ushort* __restrict__ yb)
{
    __shared__ __align__(16) char smem[131072];
    // buf b in {0,1}: K @ b*65536 (32KB: 256 rows x 128B), V^T @ +32768 (32KB: 64 rows x 512B)
    // merge scratch (110,592B) aliased @ 0 (bufs dead at merge time)
    const int tid = threadIdx.x;
    const int lane = tid & 63, wid = tid >> 6;
    const int l31 = lane & 31;
    const int hi  = lane >> 5;
    const int group = wid >> 2;          // 0..3: KV-64 slice within the 256-chunk
    const int wq    = wid & 3;           // q sub-tile
    const int subkv = group * 64;
    const int id = blockIdx.x;
    const int bh = (id & 7) * 4 + ((id >> 3) & 3);   // 4 heads per XCD slot-group
    const int qx = id >> 5;                           // 0..7
    const size_t base = (size_t)bh * 2048 * 64;
    const int b_ = bh >> 4, h_ = bh & 15;
    float* oml = (float*)smem;

    auto stageK = [&](int t, int b) {
        char* Ks = smem + b * 65536;
        #pragma unroll
        for (int it = 0; it < 2; ++it) {
            int c = it * 1024 + tid;
            int row = c >> 3, inner = c & 7;       // 256 rows x 8 chunks
            async16((const char*)kh + (base + (size_t)(t * 256 + row) * 64) * 2 + ((inner ^ (row & 7)) * 16),
                    Ks + c * 16);
        }
    };
    auto stageV = [&](int t, int b) {
        char* Vs = smem + b * 65536 + 32768;
        #pragma unroll
        for (int it = 0; it < 2; ++it) {
            int c = it * 1024 + tid;
            int row = c >> 5, inner = c & 31;      // 64 d-rows x 32 chunks
            async16((const char*)vhT + (base + (size_t)row * 2048 + (size_t)t * 256) * 2 + ((inner ^ (row & 15)) * 16),
                    Vs + c * 16);
        }
    };

    for (int p = 0; p < 2; ++p) {
        const int qt  = (p == 0) ? qx : 15 - qx;
        const int qrw = qt * 128 + wq * 32;
        const int nkv = (qt >> 1) + 1;             // chunks of 256

        // hoist Q fragments (pre-scaled by 0.125*log2e at projection)
        bf16x8 qf[4];
        #pragma unroll
        for (int ks = 0; ks < 4; ++ks)
            qf[ks] = *(const bf16x8*)((const char*)qh + (base + (size_t)(qrw + l31) * 64) * 2 + ks * 32 + hi * 16);

        f32x16 o[2];
        #pragma unroll
        for (int r = 0; r < 16; ++r) { o[0][r] = 0.f; o[1][r] = 0.f; }
        float m_run = -1e30f, l_run = 0.f;

        stageK(0, 0); stageV(0, 0);

        for (int t = 0; t < nkv; ++t) {
            const bool more = (t + 1 < nkv);
            if (more) { stageK(t + 1, (t + 1) & 1); stageV(t + 1, (t + 1) & 1); }
            PIPE_BARRIER(more);   // own t-loads done; all waves' t-loads done

            const int kv0 = t * 256 + subkv;
            if (kv0 <= qrw + 31) {
                const char* Ks = smem + (t & 1) * 65536;
                const char* Vs = Ks + 32768;

                // ---- batch ALL K-fragment reads (8 x b128, one lgkm wait at use)
                bf16x8 kf[2][4];
                #pragma unroll
                for (int tt = 0; tt < 2; ++tt)
                    #pragma unroll
                    for (int ks = 0; ks < 4; ++ks) {
                        int krow = subkv + tt * 32 + l31;
                        int byte = (krow * 128 + ks * 32 + hi * 16) ^ ((krow & 7) << 4);
                        kf[tt][ks] = *(const bf16x8*)(Ks + byte);
                    }

                // ---- QK^T (swapped): st[tt][r] over K rows kv0 + tt*32 + l31
                f32x16 st[2];
                #pragma unroll
                for (int r = 0; r < 16; ++r) { st[0][r] = 0.f; st[1][r] = 0.f; }
                __builtin_amdgcn_s_setprio(1);
                #pragma unroll
                for (int tt = 0; tt < 2; ++tt)
                    #pragma unroll
                    for (int ks = 0; ks < 4; ++ks)
                        st[tt] = mfma32(kf[tt][ks], qf[ks], st[tt]);
                __builtin_amdgcn_s_setprio(0);

                // ---- hoist ALL V-fragment reads; softmax VALU below hides latency
                bf16x8 vf[4][2];
                #pragma unroll
                for (int ks = 0; ks < 4; ++ks)
                    #pragma unroll
                    for (int dt = 0; dt < 2; ++dt) {
                        int vrow = dt * 32 + l31;
                        int byte = (vrow * 512 + subkv * 2 + ks * 32 + hi * 16) ^ ((vrow & 15) << 4);
                        vf[ks][dt] = *(const bf16x8*)(Vs + byte);
                    }

                // ---- causal mask (diagonal tiles only)
                if (kv0 + 63 > qrw) {
                    #pragma unroll
                    for (int tt = 0; tt < 2; ++tt)
                        #pragma unroll
                        for (int r = 0; r < 16; ++r) {
                            int kv = kv0 + tt * 32 + (r & 3) + 8 * (r >> 2) + 4 * hi;
                            if (kv > qrw + l31) st[tt][r] = -1e30f;
                        }
                }

                // ---- row max: tree reduction (depth 5) + cross-half
                float mx;
                {
                    float t0[8];
                    #pragma unroll
                    for (int r = 0; r < 8; ++r)
                        t0[r] = fmaxf(fmaxf(st[0][r], st[0][r + 8]),
                                      fmaxf(st[1][r], st[1][r + 8]));
                    float t1[4];
                    #pragma unroll
                    for (int r = 0; r < 4; ++r) t1[r] = fmaxf(t0[r], t0[r + 4]);
                    float t2a = fmaxf(t1[0], t1[2]), t2b = fmaxf(t1[1], t1[3]);
                    mx = fmaxf(t2a, t2b);
                }
                mx = xhalf_max(mx);

                // ---- defer-max online softmax (T13, THR=8 in log2 units)
                if (!__all(mx - m_run <= 8.0f)) {
                    float mn = fmaxf(m_run, mx);
                    float corr = __builtin_amdgcn_exp2f(m_run - mn);
                    l_run *= corr;
                    m_run = mn;
                    #pragma unroll
                    for (int r = 0; r < 16; ++r) {
                        int qsrc = (r & 3) + 8 * (r >> 2) + 4 * hi;
                        float c2 = __shfl(corr, qsrc);
                        o[0][r] *= c2; o[1][r] *= c2;
                    }
                }

                // ---- exp2 + tree sum
                #pragma unroll
                for (int tt = 0; tt < 2; ++tt)
                    #pragma unroll
                    for (int r = 0; r < 16; ++r)
                        st[tt][r] = __builtin_amdgcn_exp2f(st[tt][r] - m_run);
                float sum;
                {
                    float s0[8];
                    #pragma unroll
                    for (int r = 0; r < 8; ++r)
                        s0[r] = (st[0][r] + st[0][r + 8]) + (st[1][r] + st[1][r + 8]);
                    float s1[4];
                    #pragma unroll
                    for (int r = 0; r < 4; ++r) s1[r] = s0[r] + s0[r + 4];
                    sum = (s1[0] + s1[2]) + (s1[1] + s1[3]);
                }
                sum = xhalf_sum(sum);
                l_run += sum;

                // ---- pack P to bf16 words; exchange across halves (verified shfl_xor)
                unsigned Wd[2][8], Xw[2][8];
                #pragma unroll
                for (int tt = 0; tt < 2; ++tt)
                    #pragma unroll
                    for (int k = 0; k < 8; ++k) {
                        unsigned w;
                        asm("v_cvt_pk_bf16_f32 %0, %1, %2" : "=v"(w) : "v"(st[tt][2 * k]), "v"(st[tt][2 * k + 1]));
                        Wd[tt][k] = w;
                    }
                #pragma unroll
                for (int tt = 0; tt < 2; ++tt)
                    #pragma unroll
                    for (int k = 0; k < 8; ++k)
                        Xw[tt][k] = __shfl_xor((int)Wd[tt][k], 32);

                // ---- PV (V already in registers)
                #pragma unroll
                for (int ks = 0; ks < 4; ++ks) {
                    const int t2 = ks >> 1, bse = (ks & 1) * 4;
                    unsigned w0 = hi ? Xw[t2][bse + 2] : Wd[t2][bse + 0];
                    unsigned w1 = hi ? Xw[t2][bse + 3] : Wd[t2][bse + 1];
                    unsigned w2 = hi ? Wd[t2][bse + 2] : Xw[t2][bse + 0];
                    unsigned w3 = hi ? Wd[t2][bse + 3] : Xw[t2][bse + 1];
                    unsigned pw4[4] = {w0, w1, w2, w3};
                    bf16x8 pf = *(const bf16x8*)pw4;
                    __builtin_amdgcn_s_setprio(1);
                    #pragma unroll
                    for (int dt = 0; dt < 2; ++dt)
                        o[dt] = mfma32(pf, vf[ks][dt], o[dt]);
                    __builtin_amdgcn_s_setprio(0);
                }
            }
            END_BARRIER();   // all waves' reads of buf[t&1] done -> stage(t+2) may overwrite
        }

        // ---- 4-way merge (groups 1-3 partials in LDS, aliased over dead bufs)
        if (group != 0) {
            float* pp = oml + (size_t)((group - 1) * 256 + wq * 64 + lane) * 36;
            #pragma unroll
            for (int r = 0; r < 16; ++r) { pp[r] = o[0][r]; pp[16 + r] = o[1][r]; }
            pp[32] = m_run; pp[33] = l_run;
        }
        __syncthreads();
        if (group == 0) {
            const float* p1 = oml + (size_t)(0 * 256 + wq * 64 + lane) * 36;
            const float* p2 = oml + (size_t)(1 * 256 + wq * 64 + lane) * 36;
            const float* p3 = oml + (size_t)(2 * 256 + wq * 64 + lane) * 36;
            float m1 = p1[32], l1 = p1[33];
            float m2 = p2[32], l2 = p2[33];
            float m3 = p3[32], l3 = p3[33];
            float mn = fmaxf(fmaxf(m_run, m1), fmaxf(m2, m3));
            float a0 = __builtin_amdgcn_exp2f(m_run - mn);
            float a1 = __builtin_amdgcn_exp2f(m1 - mn);
            float a2 = __builtin_amdgcn_exp2f(m2 - mn);
            float a3 = __builtin_amdgcn_exp2f(m3 - mn);
            float lt = l_run * a0 + l1 * a1 + l2 * a2 + l3 * a3;
            float invl = 1.0f / lt;
            #pragma unroll
            for (int r = 0; r < 16; ++r) {
                int qsrc = (r & 3) + 8 * (r >> 2) + 4 * hi;
                float f0 = __shfl(a0, qsrc);
                float f1 = __shfl(a1, qsrc);
                float f2 = __shfl(a2, qsrc);
                float f3 = __shfl(a3, qsrc);
                float iv = __shfl(invl, qsrc);
                float v0 = (o[0][r] * f0 + p1[r] * f1 + p2[r] * f2 + p3[r] * f3) * iv;
                float v1 = (o[1][r] * f0 + p1[16 + r] * f1 + p2[16 + r] * f2 + p3[16 + r] * f3) * iv;
                int q = qrw + qsrc;
                size_t rowoff = ((size_t)(b_ * 2048 + q)) * 1024 + h_ * 64;
                yb[rowoff + l31]      = f2bf(v0);
                yb[rowoff + 32 + l31] = f2bf(v1);
            }
        }
        __syncthreads();
    }
}

extern "C" void kernel_launch(void* const* d_in, const int* in_sizes, int n_in,
                              void* d_out, int out_size, void* d_ws, size_t ws_size,
                              hipStream_t stream)
{
    const size_t MD = 4096ull * 1024;
    const size_t WD = 1024ull * 1024;
    ushort* ws  = (ushort*)d_ws;
    ushort* Qb  = ws;
    ushort* Kb  = Qb + MD;
    ushort* Vb  = Kb + MD;
    ushort* qhb = Vb + MD;
    ushort* khb = qhb + MD;
    ushort* vhT = khb + MD;
    ushort* WQb = vhT + MD;
    ushort* WKb = WQb + WD;
    ushort* WVb = WKb + WD;
    ushort* Wfb = WVb + WD;
    ushort* yb  = Qb;   // alias: Qb dead after QKV projection

    cvt7_kernel<<<dim3(4096, 7), 256, 0, stream>>>(
        (const float*)d_in[0], (const float*)d_in[1], (const float*)d_in[2],
        (const float*)d_in[3], (const float*)d_in[4], (const float*)d_in[5],
        (const float*)d_in[6],
        Qb, Kb, Vb, WQb, WKb, WVb, Wfb);

    gemm_qkv<<<dim3(96, 8), 256, 0, stream>>>(Qb, Kb, Vb, WQb, WKb, WVb, qhb, khb, vhT);
    attn_kernel<<<256, 1024, 0, stream>>>(qhb, khb, vhT, yb);
    gemm_fc<<<dim3(32, 8), 256, 0, stream>>>(yb, Wfb, (float*)d_out, (const float*)d_in[7]);
}

// Round 12
// 139.859 us; speedup vs baseline: 1.3084x; 1.3084x over previous
//
#include <hip/hip_runtime.h>

typedef __attribute__((ext_vector_type(8))) short bf16x8;
typedef __attribute__((ext_vector_type(4))) float f32x4;
typedef __attribute__((ext_vector_type(16))) float f32x16;

__device__ __forceinline__ ushort f2bf(float f) {
    union { float f; unsigned u; } x; x.f = f;
    unsigned r = x.u + 0x7fffu + ((x.u >> 16) & 1u);
    return (ushort)(r >> 16);
}

__device__ __forceinline__ void async16(const void* g, void* l) {
    __builtin_amdgcn_global_load_lds(
        (const __attribute__((address_space(1))) void*)g,
        (__attribute__((address_space(3))) void*)l, 16, 0, 0);
}

__device__ __forceinline__ f32x4 mfma16(bf16x8 a, bf16x8 b, f32x4 c) {
    return __builtin_amdgcn_mfma_f32_16x16x32_bf16(a, b, c, 0, 0, 0);
}
__device__ __forceinline__ f32x16 mfma32(bf16x8 a, bf16x8 b, f32x16 c) {
    return __builtin_amdgcn_mfma_f32_32x32x16_bf16(a, b, c, 0, 0, 0);
}

__device__ __forceinline__ f32x4 zero4() { f32x4 z = {0.f, 0.f, 0.f, 0.f}; return z; }

// cross-half (lane vs lane^32) reduce — VERIFIED shfl_xor form (R3-R5/R8/R9).
// NOTE: inline-asm v_permlane32_swap_b32 failed correctness in both operand
// orders (R6/R7, absmax ~4) — do not reintroduce.
__device__ __forceinline__ float xhalf_max(float v) {
    return fmaxf(v, __shfl_xor(v, 32));
}
__device__ __forceinline__ float xhalf_sum(float v) {
    return v + __shfl_xor(v, 32);
}

#define PIPE_BARRIER(cond_more)                                          \
    do {                                                                 \
        if (cond_more) asm volatile("s_waitcnt vmcnt(4)" ::: "memory");  \
        else           asm volatile("s_waitcnt vmcnt(0)" ::: "memory");  \
        asm volatile("s_waitcnt lgkmcnt(0)" ::: "memory");               \
        __builtin_amdgcn_sched_barrier(0);                               \
        __builtin_amdgcn_s_barrier();                                    \
        __builtin_amdgcn_sched_barrier(0);                               \
    } while (0)

#define END_BARRIER()                                                    \
    do {                                                                 \
        asm volatile("s_waitcnt lgkmcnt(0)" ::: "memory");               \
        __builtin_amdgcn_sched_barrier(0);                               \
        __builtin_amdgcn_s_barrier();                                    \
        __builtin_amdgcn_sched_barrier(0);                               \
    } while (0)

// -------- fused fp32 -> bf16 conversion for all 7 tensors, one launch --------
__global__ void cvt7_kernel(
    const float* __restrict__ s0, const float* __restrict__ s1, const float* __restrict__ s2,
    const float* __restrict__ s3, const float* __restrict__ s4, const float* __restrict__ s5,
    const float* __restrict__ s6,
    ushort* __restrict__ d0, ushort* __restrict__ d1, ushort* __restrict__ d2,
    ushort* __restrict__ d3, ushort* __restrict__ d4, ushort* __restrict__ d5,
    ushort* __restrict__ d6)
{
    int y = blockIdx.y;
    const float* s; ushort* d; int n4;
    if      (y == 0) { s = s0; d = d0; n4 = 1048576; }
    else if (y == 1) { s = s1; d = d1; n4 = 1048576; }
    else if (y == 2) { s = s2; d = d2; n4 = 1048576; }
    else if (y == 3) { s = s3; d = d3; n4 = 262144; }
    else if (y == 4) { s = s4; d = d4; n4 = 262144; }
    else if (y == 5) { s = s5; d = d5; n4 = 262144; }
    else             { s = s6; d = d6; n4 = 262144; }
    int i = blockIdx.x * 256 + threadIdx.x;
    if (i >= n4) return;
    float4 v = ((const float4*)s)[i];
    ushort4 o;
    o.x = f2bf(v.x); o.y = f2bf(v.y); o.z = f2bf(v.z); o.w = f2bf(v.w);
    ((ushort4*)d)[i] = o;
}

// -------- shared GEMM core: 128x128 tile, BK=32, 3-deep counted-vmcnt pipeline --------
template<bool SWAP>
__device__ __forceinline__ void gemm_core(
    const ushort* __restrict__ A, const ushort* __restrict__ W,
    char* smem, int bm, int bn, int tid, f32x4 acc[4][4])
{
    const int lane = tid & 63;
    const int wid  = tid >> 6;
    const int wr = wid >> 1, wc = wid & 1;
    const int l15 = lane & 15, g = lane >> 4;

    auto stage = [&](int kt) {
        char* As = smem + (kt % 3) * 16384;
        char* Bs = As + 8192;
        #pragma unroll
        for (int it = 0; it < 2; ++it) {
            int c = it * 256 + tid;
            int row = c >> 2, inner = c & 3;
            int srcoff = (inner ^ (row & 3)) * 16;
            async16((const char*)A + (size_t)(bm * 128 + row) * 2048 + kt * 64 + srcoff, As + c * 16);
            async16((const char*)W + (size_t)(bn * 128 + row) * 2048 + kt * 64 + srcoff, Bs + c * 16);
        }
    };

    stage(0);
    stage(1);

    for (int kt = 0; kt < 32; ++kt) {
        PIPE_BARRIER(kt < 31);
        if (kt < 30) stage(kt + 2);

        const char* As = smem + (kt % 3) * 16384;
        const char* Bs = As + 8192;
        bf16x8 af[4], bfr[4];
        #pragma unroll
        for (int mt = 0; mt < 4; ++mt) {
            int row = wr * 64 + mt * 16 + l15;
            af[mt] = *(const bf16x8*)(As + ((row * 64 + g * 16) ^ ((row & 3) << 4)));
        }
        #pragma unroll
        for (int nt = 0; nt < 4; ++nt) {
            int row = wc * 64 + nt * 16 + l15;
            bfr[nt] = *(const bf16x8*)(Bs + ((row * 64 + g * 16) ^ ((row & 3) << 4)));
        }
        __builtin_amdgcn_s_setprio(1);
        #pragma unroll
        for (int mt = 0; mt < 4; ++mt)
            #pragma unroll
            for (int nt = 0; nt < 4; ++nt) {
                if (SWAP) acc[mt][nt] = mfma16(bfr[nt], af[mt], acc[mt][nt]);
                else      acc[mt][nt] = mfma16(af[mt], bfr[nt], acc[mt][nt]);
            }
        __builtin_amdgcn_s_setprio(0);
    }
}

// -------- merged QKV projection: grid (96, 8), z = x%3 --------
// Q scaled by 0.125*log2(e) (exp2-domain softmax downstream).
__global__ __launch_bounds__(256, 2) void gemm_qkv(
    const ushort* __restrict__ Qb, const ushort* __restrict__ Kb, const ushort* __restrict__ Vb,
    const ushort* __restrict__ WQ, const ushort* __restrict__ WK, const ushort* __restrict__ WV,
    ushort* __restrict__ qhb, ushort* __restrict__ khb, ushort* __restrict__ vhT)
{
    __shared__ __align__(16) char smem[49152];
    const int tid = threadIdx.x;
    const int z  = blockIdx.x % 3;
    const int bm = blockIdx.x / 3;
    const int bn = blockIdx.y;
    const int lane = tid & 63;
    const int wid  = tid >> 6;
    const int wr = wid >> 1, wc = wid & 1;
    const int l15 = lane & 15, g = lane >> 4;

    const ushort* A  = (z == 0) ? Qb : (z == 1) ? Kb : Vb;
    const ushort* Wm = (z == 0) ? WQ : (z == 1) ? WK : WV;

    f32x4 acc[4][4];
    #pragma unroll
    for (int i = 0; i < 4; ++i)
        #pragma unroll
        for (int j = 0; j < 4; ++j) acc[i][j] = zero4();

    if (z == 2) {
        gemm_core<true>(A, Wm, smem, bm, bn, tid, acc);
        #pragma unroll
        for (int mt = 0; mt < 4; ++mt)
            #pragma unroll
            for (int nt = 0; nt < 4; ++nt)
                #pragma unroll
                for (int j = 0; j < 4; ++j) {
                    int n = bn * 128 + wc * 64 + nt * 16 + g * 4 + j;
                    int m = bm * 128 + wr * 64 + mt * 16 + l15;
                    int b = m >> 11, s = m & 2047, h = (n >> 6) & 15, d = n & 63;
                    vhT[(((size_t)(b * 16 + h)) * 64 + d) * 2048 + s] = f2bf(acc[mt][nt][j]);
                }
    } else {
        gemm_core<false>(A, Wm, smem, bm, bn, tid, acc);
        const float scale = (z == 0) ? 0.18033688011112042f : 1.0f;  // 0.125 * log2(e)
        ushort* outb = (z == 0) ? qhb : khb;
        #pragma unroll
        for (int mt = 0; mt < 4; ++mt)
            #pragma unroll
            for (int nt = 0; nt < 4; ++nt)
                #pragma unroll
                for (int j = 0; j < 4; ++j) {
                    int m = bm * 128 + wr * 64 + mt * 16 + g * 4 + j;
                    int n = bn * 128 + wc * 64 + nt * 16 + l15;
                    int b = m >> 11, s = m & 2047, h = n >> 6, d = n & 63;
                    outb[(((size_t)(b * 16 + h)) * 2048 + s) * 64 + d] = f2bf(acc[mt][nt][j] * scale);
                }
    }
}

// -------- final GEMM: out = A @ W^T + bias (fp32 out) --------
__global__ __launch_bounds__(256, 2) void gemm_fc(
    const ushort* __restrict__ A, const ushort* __restrict__ W,
    float* __restrict__ outf, const float* __restrict__ bias)
{
    __shared__ __align__(16) char smem[49152];
    const int tid = threadIdx.x;
    const int lane = tid & 63;
    const int wid  = tid >> 6;
    const int wr = wid >> 1, wc = wid & 1;
    const int l15 = lane & 15, g = lane >> 4;

    f32x4 acc[4][4];
    #pragma unroll
    for (int i = 0; i < 4; ++i)
        #pragma unroll
        for (int j = 0; j < 4; ++j) acc[i][j] = zero4();

    gemm_core<false>(A, W, smem, blockIdx.x, blockIdx.y, tid, acc);

    #pragma unroll
    for (int mt = 0; mt < 4; ++mt)
        #pragma unroll
        for (int nt = 0; nt < 4; ++nt)
            #pragma unroll
            for (int j = 0; j < 4; ++j) {
                int m = blockIdx.x * 128 + wr * 64 + mt * 16 + g * 4 + j;
                int n = blockIdx.y * 128 + wc * 64 + nt * 16 + l15;
                outf[(size_t)m * 1024 + n] = acc[mt][nt][j] + bias[n];
            }
}

// -------- causal flash attention --------
// grid 512 1-D, block 512 = 8 waves. ONE q-tile per block (no pair loop).
// id mapping: blocks c and c+256 (round-robin colocated) get qt and 15-qt
// -> every CU's pair totals 17 iters. XCD-aware bh decode.
// Waves 0-3: even KV-64 half of the 128-chunk; waves 4-7: odd half.
// 2-deep counted-vmcnt pipeline, 64KB LDS -> 2 blocks/CU; reg cap 128
// (launch_bounds(512,4)) matched to trimmed body (kf read per-tt, -16 regs).
__global__ __launch_bounds__(512, 4) void attn_kernel(
    const ushort* __restrict__ qh, const ushort* __restrict__ kh,
    const ushort* __restrict__ vhT, ushort* __restrict__ yb)
{
    __shared__ __align__(16) char smem[65536];
    // buf b in {0,1}: K @ b*32768 (16KB), V^T @ b*32768+16384 (16KB)
    // merge scratch (36,864B) aliased @ 0 (bufs dead at merge time)
    const int tid = threadIdx.x;
    const int lane = tid & 63, wid = tid >> 6;
    const int l31 = lane & 31;
    const int hi  = lane >> 5;
    const int group = wid >> 2;          // 0 = even KV-64 half, 1 = odd
    const int wq    = wid & 3;
    const int subkv = group * 64;
    const int id = blockIdx.x;
    const int lo = id & 255;
    const int bh = (lo & 7) * 4 + ((lo >> 3) & 3);   // 4 heads per XCD slot-group
    const int qt = (id < 256) ? (lo >> 5) : 15 - (lo >> 5);
    const size_t base = (size_t)bh * 2048 * 64;
    const int b_ = bh >> 4, h_ = bh & 15;
    const int qrw = qt * 128 + wq * 32;
    float* oml = (float*)smem;

    auto stageK = [&](int t, int b) {
        char* Ks = smem + b * 32768;
        #pragma unroll
        for (int it = 0; it < 2; ++it) {
            int c = it * 512 + tid;
            int row = c >> 3, inner = c & 7;
            async16((const char*)kh + (base + (size_t)(t * 128 + row) * 64) * 2 + ((inner ^ (row & 7)) * 16),
                    Ks + c * 16);
        }
    };
    auto stageV = [&](int t, int b) {
        char* Vs = smem + b * 32768 + 16384;
        #pragma unroll
        for (int it = 0; it < 2; ++it) {
            int c = it * 512 + tid;
            int row = c >> 4, inner = c & 15;   // row = d
            async16((const char*)vhT + (base + (size_t)row * 2048 + (size_t)t * 128) * 2 + ((inner ^ (row & 15)) * 16),
                    Vs + c * 16);
        }
    };

    // hoist Q fragments (pre-scaled by 0.125*log2e at projection)
    bf16x8 qf[4];
    #pragma unroll
    for (int ks = 0; ks < 4; ++ks)
        qf[ks] = *(const bf16x8*)((const char*)qh + (base + (size_t)(qrw + l31) * 64) * 2 + ks * 32 + hi * 16);

    f32x16 o[2];
    #pragma unroll
    for (int r = 0; r < 16; ++r) { o[0][r] = 0.f; o[1][r] = 0.f; }
    float m_run = -1e30f, l_run = 0.f;

    stageK(0, 0); stageV(0, 0);

    for (int t = 0; t <= qt; ++t) {
        const bool more = (t + 1 <= qt);
        if (more) { stageK(t + 1, (t + 1) & 1); stageV(t + 1, (t + 1) & 1); }
        PIPE_BARRIER(more);

        const int kv0 = t * 128 + subkv;
        if (kv0 <= qrw + 31) {
            const char* Ks = smem + (t & 1) * 32768;
            const char* Vs = Ks + 16384;

            // ---- QK^T (swapped), K-fragments batched per-tt (reg trim vs R9)
            f32x16 st[2];
            #pragma unroll
            for (int r = 0; r < 16; ++r) { st[0][r] = 0.f; st[1][r] = 0.f; }
            #pragma unroll
            for (int tt = 0; tt < 2; ++tt) {
                bf16x8 kf[4];
                #pragma unroll
                for (int ks = 0; ks < 4; ++ks) {
                    int krow = subkv + tt * 32 + l31;
                    int byte = (krow * 128 + ks * 32 + hi * 16) ^ ((krow & 7) << 4);
                    kf[ks] = *(const bf16x8*)(Ks + byte);
                }
                __builtin_amdgcn_s_setprio(1);
                #pragma unroll
                for (int ks = 0; ks < 4; ++ks)
                    st[tt] = mfma32(kf[ks], qf[ks], st[tt]);
                __builtin_amdgcn_s_setprio(0);
            }

            // ---- hoist ALL V-fragment reads; softmax VALU below hides latency
            bf16x8 vf[4][2];
            #pragma unroll
            for (int ks = 0; ks < 4; ++ks)
                #pragma unroll
                for (int dt = 0; dt < 2; ++dt) {
                    int vrow = dt * 32 + l31;
                    int colB = subkv * 2 + ks * 32 + hi * 16;
                    int byte = vrow * 256 + (colB ^ ((vrow & 15) << 4));
                    vf[ks][dt] = *(const bf16x8*)(Vs + byte);
                }

            // ---- causal mask (diagonal tiles only)
            if (kv0 + 63 > qrw) {
                #pragma unroll
                for (int tt = 0; tt < 2; ++tt)
                    #pragma unroll
                    for (int r = 0; r < 16; ++r) {
                        int kv = kv0 + tt * 32 + (r & 3) + 8 * (r >> 2) + 4 * hi;
                        if (kv > qrw + l31) st[tt][r] = -1e30f;
                    }
            }

            // ---- row max: tree reduction + cross-half
            float mx;
            {
                float t0[8];
                #pragma unroll
                for (int r = 0; r < 8; ++r)
                    t0[r] = fmaxf(fmaxf(st[0][r], st[0][r + 8]),
                                  fmaxf(st[1][r], st[1][r + 8]));
                float t1[4];
                #pragma unroll
                for (int r = 0; r < 4; ++r) t1[r] = fmaxf(t0[r], t0[r + 4]);
                mx = fmaxf(fmaxf(t1[0], t1[2]), fmaxf(t1[1], t1[3]));
            }
            mx = xhalf_max(mx);

            // ---- defer-max online softmax (T13, THR=8 in log2 units)
            if (!__all(mx - m_run <= 8.0f)) {
                float mn = fmaxf(m_run, mx);
                float corr = __builtin_amdgcn_exp2f(m_run - mn);
                l_run *= corr;
                m_run = mn;
                #pragma unroll
                for (int r = 0; r < 16; ++r) {
                    int qsrc = (r & 3) + 8 * (r >> 2) + 4 * hi;
                    float c2 = __shfl(corr, qsrc);
                    o[0][r] *= c2; o[1][r] *= c2;
                }
            }

            // ---- exp2 + tree sum
            #pragma unroll
            for (int tt = 0; tt < 2; ++tt)
                #pragma unroll
                for (int r = 0; r < 16; ++r)
                    st[tt][r] = __builtin_amdgcn_exp2f(st[tt][r] - m_run);
            float sum;
            {
                float s0[8];
                #pragma unroll
                for (int r = 0; r < 8; ++r)
                    s0[r] = (st[0][r] + st[0][r + 8]) + (st[1][r] + st[1][r + 8]);
                float s1[4];
                #pragma unroll
                for (int r = 0; r < 4; ++r) s1[r] = s0[r] + s0[r + 4];
                sum = (s1[0] + s1[2]) + (s1[1] + s1[3]);
            }
            sum = xhalf_sum(sum);
            l_run += sum;

            // ---- pack P to bf16 words; exchange across halves (verified shfl_xor)
            unsigned Wd[2][8], Xw[2][8];
            #pragma unroll
            for (int tt = 0; tt < 2; ++tt)
                #pragma unroll
                for (int k = 0; k < 8; ++k) {
                    unsigned w;
                    asm("v_cvt_pk_bf16_f32 %0, %1, %2" : "=v"(w) : "v"(st[tt][2 * k]), "v"(st[tt][2 * k + 1]));
                    Wd[tt][k] = w;
                }
            #pragma unroll
            for (int tt = 0; tt < 2; ++tt)
                #pragma unroll
                for (int k = 0; k < 8; ++k)
                    Xw[tt][k] = __shfl_xor((int)Wd[tt][k], 32);

            // ---- PV (V already in registers)
            #pragma unroll
            for (int ks = 0; ks < 4; ++ks) {
                const int t2 = ks >> 1, bse = (ks & 1) * 4;
                unsigned w0 = hi ? Xw[t2][bse + 2] : Wd[t2][bse + 0];
                unsigned w1 = hi ? Xw[t2][bse + 3] : Wd[t2][bse + 1];
                unsigned w2 = hi ? Wd[t2][bse + 2] : Xw[t2][bse + 0];
                unsigned w3 = hi ? Wd[t2][bse + 3] : Xw[t2][bse + 1];
                unsigned pw4[4] = {w0, w1, w2, w3};
                bf16x8 pf = *(const bf16x8*)pw4;
                __builtin_amdgcn_s_setprio(1);
                #pragma unroll
                for (int dt = 0; dt < 2; ++dt)
                    o[dt] = mfma32(pf, vf[ks][dt], o[dt]);
                __builtin_amdgcn_s_setprio(0);
            }
        }
        END_BARRIER();
    }

    // ---- merge the two KV halves (oml aliased over dead bufs), store q-tile
    if (group == 1) {
        float* pp = oml + (size_t)(wq * 64 + lane) * 36;
        #pragma unroll
        for (int r = 0; r < 16; ++r) { pp[r] = o[0][r]; pp[16 + r] = o[1][r]; }
        pp[32] = m_run; pp[33] = l_run;
    }
    __syncthreads();
    if (group == 0) {
        const float* pp = oml + (size_t)(wq * 64 + lane) * 36;
        float m1 = pp[32], l1 = pp[33];
        float mn = fmaxf(m_run, m1);
        float a0 = __builtin_amdgcn_exp2f(m_run - mn);
        float a1 = __builtin_amdgcn_exp2f(m1 - mn);
        float lt = l_run * a0 + l1 * a1;
        float invl = 1.0f / lt;
        #pragma unroll
        for (int r = 0; r < 16; ++r) {
            int qsrc = (r & 3) + 8 * (r >> 2) + 4 * hi;
            float f0 = __shfl(a0, qsrc);
            float f1 = __shfl(a1, qsrc);
            float iv = __shfl(invl, qsrc);
            float v0 = (o[0][r] * f0 + pp[r] * f1) * iv;
            float v1 = (o[1][r] * f0 + pp[16 + r] * f1) * iv;
            int q = qrw + qsrc;
            size_t rowoff = ((size_t)(b_ * 2048 + q)) * 1024 + h_ * 64;
            yb[rowoff + l31]      = f2bf(v0);
            yb[rowoff + 32 + l31] = f2bf(v1);
        }
    }
}

extern "C" void kernel_launch(void* const* d_in, const int* in_sizes, int n_in,
                              void* d_out, int out_size, void* d_ws, size_t ws_size,
                              hipStream_t stream)
{
    const size_t MD = 4096ull * 1024;
    const size_t WD = 1024ull * 1024;
    ushort* ws  = (ushort*)d_ws;
    ushort* Qb  = ws;
    ushort* Kb  = Qb + MD;
    ushort* Vb  = Kb + MD;
    ushort* qhb = Vb + MD;
    ushort* khb = qhb + MD;
    ushort* vhT = khb + MD;
    ushort* WQb = vhT + MD;
    ushort* WKb = WQb + WD;
    ushort* WVb = WKb + WD;
    ushort* Wfb = WVb + WD;
    ushort* yb  = Qb;   // alias: Qb dead after QKV projection

    cvt7_kernel<<<dim3(4096, 7), 256, 0, stream>>>(
        (const float*)d_in[0], (const float*)d_in[1], (const float*)d_in[2],
        (const float*)d_in[3], (const float*)d_in[4], (const float*)d_in[5],
        (const float*)d_in[6],
        Qb, Kb, Vb, WQb, WKb, WVb, Wfb);

    gemm_qkv<<<dim3(96, 8), 256, 0, stream>>>(Qb, Kb, Vb, WQb, WKb, WVb, qhb, khb, vhT);
    attn_kernel<<<512, 512, 0, stream>>>(qhb, khb, vhT, yb);
    gemm_fc<<<dim3(32, 8), 256, 0, stream>>>(yb, Wfb, (float*)d_out, (const float*)d_in[7]);
}

// Round 13
// 107.792 us; speedup vs baseline: 1.6976x; 1.2975x over previous
//
#include <hip/hip_runtime.h>

typedef __attribute__((ext_vector_type(8))) short bf16x8;
typedef __attribute__((ext_vector_type(4))) float f32x4;
typedef __attribute__((ext_vector_type(16))) float f32x16;

__device__ __forceinline__ ushort f2bf(float f) {
    union { float f; unsigned u; } x; x.f = f;
    unsigned r = x.u + 0x7fffu + ((x.u >> 16) & 1u);
    return (ushort)(r >> 16);
}

__device__ __forceinline__ void async16(const void* g, void* l) {
    __builtin_amdgcn_global_load_lds(
        (const __attribute__((address_space(1))) void*)g,
        (__attribute__((address_space(3))) void*)l, 16, 0, 0);
}

__device__ __forceinline__ f32x4 mfma16(bf16x8 a, bf16x8 b, f32x4 c) {
    return __builtin_amdgcn_mfma_f32_16x16x32_bf16(a, b, c, 0, 0, 0);
}
__device__ __forceinline__ f32x16 mfma32(bf16x8 a, bf16x8 b, f32x16 c) {
    return __builtin_amdgcn_mfma_f32_32x32x16_bf16(a, b, c, 0, 0, 0);
}

__device__ __forceinline__ f32x4 zero4() { f32x4 z = {0.f, 0.f, 0.f, 0.f}; return z; }

// cross-half (lane vs lane^32) reduce — VERIFIED shfl_xor form (R3-R5/R8/R9).
// NOTE: inline-asm v_permlane32_swap_b32 failed correctness in both operand
// orders (R6/R7, absmax ~4) — do not reintroduce.
__device__ __forceinline__ float xhalf_max(float v) {
    return fmaxf(v, __shfl_xor(v, 32));
}
__device__ __forceinline__ float xhalf_sum(float v) {
    return v + __shfl_xor(v, 32);
}

#define PIPE_BARRIER(cond_more)                                          \
    do {                                                                 \
        if (cond_more) asm volatile("s_waitcnt vmcnt(4)" ::: "memory");  \
        else           asm volatile("s_waitcnt vmcnt(0)" ::: "memory");  \
        asm volatile("s_waitcnt lgkmcnt(0)" ::: "memory");               \
        __builtin_amdgcn_sched_barrier(0);                               \
        __builtin_amdgcn_s_barrier();                                    \
        __builtin_amdgcn_sched_barrier(0);                               \
    } while (0)

#define END_BARRIER()                                                    \
    do {                                                                 \
        asm volatile("s_waitcnt lgkmcnt(0)" ::: "memory");               \
        __builtin_amdgcn_sched_barrier(0);                               \
        __builtin_amdgcn_s_barrier();                                    \
        __builtin_amdgcn_sched_barrier(0);                               \
    } while (0)

// -------- fused fp32 -> bf16 conversion for all 7 tensors, one launch --------
__global__ void cvt7_kernel(
    const float* __restrict__ s0, const float* __restrict__ s1, const float* __restrict__ s2,
    const float* __restrict__ s3, const float* __restrict__ s4, const float* __restrict__ s5,
    const float* __restrict__ s6,
    ushort* __restrict__ d0, ushort* __restrict__ d1, ushort* __restrict__ d2,
    ushort* __restrict__ d3, ushort* __restrict__ d4, ushort* __restrict__ d5,
    ushort* __restrict__ d6)
{
    int y = blockIdx.y;
    const float* s; ushort* d; int n4;
    if      (y == 0) { s = s0; d = d0; n4 = 1048576; }
    else if (y == 1) { s = s1; d = d1; n4 = 1048576; }
    else if (y == 2) { s = s2; d = d2; n4 = 1048576; }
    else if (y == 3) { s = s3; d = d3; n4 = 262144; }
    else if (y == 4) { s = s4; d = d4; n4 = 262144; }
    else if (y == 5) { s = s5; d = d5; n4 = 262144; }
    else             { s = s6; d = d6; n4 = 262144; }
    int i = blockIdx.x * 256 + threadIdx.x;
    if (i >= n4) return;
    float4 v = ((const float4*)s)[i];
    ushort4 o;
    o.x = f2bf(v.x); o.y = f2bf(v.y); o.z = f2bf(v.z); o.w = f2bf(v.w);
    ((ushort4*)d)[i] = o;
}

// -------- shared GEMM core: 128x128 tile, BK=32, 3-deep counted-vmcnt pipeline --------
template<bool SWAP>
__device__ __forceinline__ void gemm_core(
    const ushort* __restrict__ A, const ushort* __restrict__ W,
    char* smem, int bm, int bn, int tid, f32x4 acc[4][4])
{
    const int lane = tid & 63;
    const int wid  = tid >> 6;
    const int wr = wid >> 1, wc = wid & 1;
    const int l15 = lane & 15, g = lane >> 4;

    auto stage = [&](int kt) {
        char* As = smem + (kt % 3) * 16384;
        char* Bs = As + 8192;
        #pragma unroll
        for (int it = 0; it < 2; ++it) {
            int c = it * 256 + tid;
            int row = c >> 2, inner = c & 3;
            int srcoff = (inner ^ (row & 3)) * 16;
            async16((const char*)A + (size_t)(bm * 128 + row) * 2048 + kt * 64 + srcoff, As + c * 16);
            async16((const char*)W + (size_t)(bn * 128 + row) * 2048 + kt * 64 + srcoff, Bs + c * 16);
        }
    };

    stage(0);
    stage(1);

    for (int kt = 0; kt < 32; ++kt) {
        PIPE_BARRIER(kt < 31);
        if (kt < 30) stage(kt + 2);

        const char* As = smem + (kt % 3) * 16384;
        const char* Bs = As + 8192;
        bf16x8 af[4], bfr[4];
        #pragma unroll
        for (int mt = 0; mt < 4; ++mt) {
            int row = wr * 64 + mt * 16 + l15;
            af[mt] = *(const bf16x8*)(As + ((row * 64 + g * 16) ^ ((row & 3) << 4)));
        }
        #pragma unroll
        for (int nt = 0; nt < 4; ++nt) {
            int row = wc * 64 + nt * 16 + l15;
            bfr[nt] = *(const bf16x8*)(Bs + ((row * 64 + g * 16) ^ ((row & 3) << 4)));
        }
        __builtin_amdgcn_s_setprio(1);
        #pragma unroll
        for (int mt = 0; mt < 4; ++mt)
            #pragma unroll
            for (int nt = 0; nt < 4; ++nt) {
                if (SWAP) acc[mt][nt] = mfma16(bfr[nt], af[mt], acc[mt][nt]);
                else      acc[mt][nt] = mfma16(af[mt], bfr[nt], acc[mt][nt]);
            }
        __builtin_amdgcn_s_setprio(0);
    }
}

// -------- merged QKV projection: grid (96, 8), z = x%3 --------
// Q scaled by 0.125*log2(e) (exp2-domain softmax downstream).
__global__ __launch_bounds__(256, 2) void gemm_qkv(
    const ushort* __restrict__ Qb, const ushort* __restrict__ Kb, const ushort* __restrict__ Vb,
    const ushort* __restrict__ WQ, const ushort* __restrict__ WK, const ushort* __restrict__ WV,
    ushort* __restrict__ qhb, ushort* __restrict__ khb, ushort* __restrict__ vhT)
{
    __shared__ __align__(16) char smem[49152];
    const int tid = threadIdx.x;
    const int z  = blockIdx.x % 3;
    const int bm = blockIdx.x / 3;
    const int bn = blockIdx.y;
    const int lane = tid & 63;
    const int wid  = tid >> 6;
    const int wr = wid >> 1, wc = wid & 1;
    const int l15 = lane & 15, g = lane >> 4;

    const ushort* A  = (z == 0) ? Qb : (z == 1) ? Kb : Vb;
    const ushort* Wm = (z == 0) ? WQ : (z == 1) ? WK : WV;

    f32x4 acc[4][4];
    #pragma unroll
    for (int i = 0; i < 4; ++i)
        #pragma unroll
        for (int j = 0; j < 4; ++j) acc[i][j] = zero4();

    if (z == 2) {
        gemm_core<true>(A, Wm, smem, bm, bn, tid, acc);
        #pragma unroll
        for (int mt = 0; mt < 4; ++mt)
            #pragma unroll
            for (int nt = 0; nt < 4; ++nt)
                #pragma unroll
                for (int j = 0; j < 4; ++j) {
                    int n = bn * 128 + wc * 64 + nt * 16 + g * 4 + j;
                    int m = bm * 128 + wr * 64 + mt * 16 + l15;
                    int b = m >> 11, s = m & 2047, h = (n >> 6) & 15, d = n & 63;
                    vhT[(((size_t)(b * 16 + h)) * 64 + d) * 2048 + s] = f2bf(acc[mt][nt][j]);
                }
    } else {
        gemm_core<false>(A, Wm, smem, bm, bn, tid, acc);
        const float scale = (z == 0) ? 0.18033688011112042f : 1.0f;  // 0.125 * log2(e)
        ushort* outb = (z == 0) ? qhb : khb;
        #pragma unroll
        for (int mt = 0; mt < 4; ++mt)
            #pragma unroll
            for (int nt = 0; nt < 4; ++nt)
                #pragma unroll
                for (int j = 0; j < 4; ++j) {
                    int m = bm * 128 + wr * 64 + mt * 16 + g * 4 + j;
                    int n = bn * 128 + wc * 64 + nt * 16 + l15;
                    int b = m >> 11, s = m & 2047, h = n >> 6, d = n & 63;
                    outb[(((size_t)(b * 16 + h)) * 2048 + s) * 64 + d] = f2bf(acc[mt][nt][j] * scale);
                }
    }
}

// -------- final GEMM: out = A @ W^T + bias (fp32 out) --------
__global__ __launch_bounds__(256, 2) void gemm_fc(
    const ushort* __restrict__ A, const ushort* __restrict__ W,
    float* __restrict__ outf, const float* __restrict__ bias)
{
    __shared__ __align__(16) char smem[49152];
    const int tid = threadIdx.x;
    const int lane = tid & 63;
    const int wid  = tid >> 6;
    const int wr = wid >> 1, wc = wid & 1;
    const int l15 = lane & 15, g = lane >> 4;

    f32x4 acc[4][4];
    #pragma unroll
    for (int i = 0; i < 4; ++i)
        #pragma unroll
        for (int j = 0; j < 4; ++j) acc[i][j] = zero4();

    gemm_core<false>(A, W, smem, blockIdx.x, blockIdx.y, tid, acc);

    #pragma unroll
    for (int mt = 0; mt < 4; ++mt)
        #pragma unroll
        for (int nt = 0; nt < 4; ++nt)
            #pragma unroll
            for (int j = 0; j < 4; ++j) {
                int m = blockIdx.x * 128 + wr * 64 + mt * 16 + g * 4 + j;
                int n = blockIdx.y * 128 + wc * 64 + nt * 16 + l15;
                outf[(size_t)m * 1024 + n] = acc[mt][nt][j] + bias[n];
            }
}

// -------- causal flash attention --------
// grid 512 1-D, block 512 = 8 waves. ONE q-tile per block.
// id mapping: blocks c and c+256 (round-robin colocated) get qt and 15-qt
// -> every CU's pair totals 17 iters. XCD-aware bh decode.
// R13: __launch_bounds__(512, 2) — empirically arg2 behaves like CUDA's
// min-BLOCKS-per-CU on this toolchain (R10-R12 all clamped VGPR to 64 =
// 8 waves/SIMD and spilled ~40 regs -> 178MB scratch FETCH). (512,2) =
// 16 waves/CU = 4 waves/SIMD -> VGPR cap 128 >= body (~110): no spill,
// 2 independent blocks/CU for real TLP against the serial chain.
__global__ __launch_bounds__(512, 2) void attn_kernel(
    const ushort* __restrict__ qh, const ushort* __restrict__ kh,
    const ushort* __restrict__ vhT, ushort* __restrict__ yb)
{
    __shared__ __align__(16) char smem[65536];
    // buf b in {0,1}: K @ b*32768 (16KB), V^T @ b*32768+16384 (16KB)
    // merge scratch (36,864B) aliased @ 0 (bufs dead at merge time)
    const int tid = threadIdx.x;
    const int lane = tid & 63, wid = tid >> 6;
    const int l31 = lane & 31;
    const int hi  = lane >> 5;
    const int group = wid >> 2;          // 0 = even KV-64 half, 1 = odd
    const int wq    = wid & 3;
    const int subkv = group * 64;
    const int id = blockIdx.x;
    const int lo = id & 255;
    const int bh = (lo & 7) * 4 + ((lo >> 3) & 3);   // 4 heads per XCD slot-group
    const int qt = (id < 256) ? (lo >> 5) : 15 - (lo >> 5);
    const size_t base = (size_t)bh * 2048 * 64;
    const int b_ = bh >> 4, h_ = bh & 15;
    const int qrw = qt * 128 + wq * 32;
    float* oml = (float*)smem;

    auto stageK = [&](int t, int b) {
        char* Ks = smem + b * 32768;
        #pragma unroll
        for (int it = 0; it < 2; ++it) {
            int c = it * 512 + tid;
            int row = c >> 3, inner = c & 7;
            async16((const char*)kh + (base + (size_t)(t * 128 + row) * 64) * 2 + ((inner ^ (row & 7)) * 16),
                    Ks + c * 16);
        }
    };
    auto stageV = [&](int t, int b) {
        char* Vs = smem + b * 32768 + 16384;
        #pragma unroll
        for (int it = 0; it < 2; ++it) {
            int c = it * 512 + tid;
            int row = c >> 4, inner = c & 15;   // row = d
            async16((const char*)vhT + (base + (size_t)row * 2048 + (size_t)t * 128) * 2 + ((inner ^ (row & 15)) * 16),
                    Vs + c * 16);
        }
    };

    // hoist Q fragments (pre-scaled by 0.125*log2e at projection)
    bf16x8 qf[4];
    #pragma unroll
    for (int ks = 0; ks < 4; ++ks)
        qf[ks] = *(const bf16x8*)((const char*)qh + (base + (size_t)(qrw + l31) * 64) * 2 + ks * 32 + hi * 16);

    f32x16 o[2];
    #pragma unroll
    for (int r = 0; r < 16; ++r) { o[0][r] = 0.f; o[1][r] = 0.f; }
    float m_run = -1e30f, l_run = 0.f;

    stageK(0, 0); stageV(0, 0);

    for (int t = 0; t <= qt; ++t) {
        const bool more = (t + 1 <= qt);
        if (more) { stageK(t + 1, (t + 1) & 1); stageV(t + 1, (t + 1) & 1); }
        PIPE_BARRIER(more);

        const int kv0 = t * 128 + subkv;
        if (kv0 <= qrw + 31) {
            const char* Ks = smem + (t & 1) * 32768;
            const char* Vs = Ks + 16384;

            // ---- QK^T (swapped), K-fragments batched per-tt
            f32x16 st[2];
            #pragma unroll
            for (int r = 0; r < 16; ++r) { st[0][r] = 0.f; st[1][r] = 0.f; }
            #pragma unroll
            for (int tt = 0; tt < 2; ++tt) {
                bf16x8 kf[4];
                #pragma unroll
                for (int ks = 0; ks < 4; ++ks) {
                    int krow = subkv + tt * 32 + l31;
                    int byte = (krow * 128 + ks * 32 + hi * 16) ^ ((krow & 7) << 4);
                    kf[ks] = *(const bf16x8*)(Ks + byte);
                }
                __builtin_amdgcn_s_setprio(1);
                #pragma unroll
                for (int ks = 0; ks < 4; ++ks)
                    st[tt] = mfma32(kf[ks], qf[ks], st[tt]);
                __builtin_amdgcn_s_setprio(0);
            }

            // ---- hoist ALL V-fragment reads; softmax VALU below hides latency
            bf16x8 vf[4][2];
            #pragma unroll
            for (int ks = 0; ks < 4; ++ks)
                #pragma unroll
                for (int dt = 0; dt < 2; ++dt) {
                    int vrow = dt * 32 + l31;
                    int colB = subkv * 2 + ks * 32 + hi * 16;
                    int byte = vrow * 256 + (colB ^ ((vrow & 15) << 4));
                    vf[ks][dt] = *(const bf16x8*)(Vs + byte);
                }

            // ---- causal mask (diagonal tiles only)
            if (kv0 + 63 > qrw) {
                #pragma unroll
                for (int tt = 0; tt < 2; ++tt)
                    #pragma unroll
                    for (int r = 0; r < 16; ++r) {
                        int kv = kv0 + tt * 32 + (r & 3) + 8 * (r >> 2) + 4 * hi;
                        if (kv > qrw + l31) st[tt][r] = -1e30f;
                    }
            }

            // ---- row max: tree reduction + cross-half
            float mx;
            {
                float t0[8];
                #pragma unroll
                for (int r = 0; r < 8; ++r)
                    t0[r] = fmaxf(fmaxf(st[0][r], st[0][r + 8]),
                                  fmaxf(st[1][r], st[1][r + 8]));
                float t1[4];
                #pragma unroll
                for (int r = 0; r < 4; ++r) t1[r] = fmaxf(t0[r], t0[r + 4]);
                mx = fmaxf(fmaxf(t1[0], t1[2]), fmaxf(t1[1], t1[3]));
            }
            mx = xhalf_max(mx);

            // ---- defer-max online softmax (T13, THR=8 in log2 units)
            if (!__all(mx - m_run <= 8.0f)) {
                float mn = fmaxf(m_run, mx);
                float corr = __builtin_amdgcn_exp2f(m_run - mn);
                l_run *= corr;
                m_run = mn;
                #pragma unroll
                for (int r = 0; r < 16; ++r) {
                    int qsrc = (r & 3) + 8 * (r >> 2) + 4 * hi;
                    float c2 = __shfl(corr, qsrc);
                    o[0][r] *= c2; o[1][r] *= c2;
                }
            }

            // ---- exp2 + tree sum
            #pragma unroll
            for (int tt = 0; tt < 2; ++tt)
                #pragma unroll
                for (int r = 0; r < 16; ++r)
                    st[tt][r] = __builtin_amdgcn_exp2f(st[tt][r] - m_run);
            float sum;
            {
                float s0[8];
                #pragma unroll
                for (int r = 0; r < 8; ++r)
                    s0[r] = (st[0][r] + st[0][r + 8]) + (st[1][r] + st[1][r + 8]);
                float s1[4];
                #pragma unroll
                for (int r = 0; r < 4; ++r) s1[r] = s0[r] + s0[r + 4];
                sum = (s1[0] + s1[2]) + (s1[1] + s1[3]);
            }
            sum = xhalf_sum(sum);
            l_run += sum;

            // ---- pack P to bf16 words; exchange across halves (verified shfl_xor)
            unsigned Wd[2][8], Xw[2][8];
            #pragma unroll
            for (int tt = 0; tt < 2; ++tt)
                #pragma unroll
                for (int k = 0; k < 8; ++k) {
                    unsigned w;
                    asm("v_cvt_pk_bf16_f32 %0, %1, %2" : "=v"(w) : "v"(st[tt][2 * k]), "v"(st[tt][2 * k + 1]));
                    Wd[tt][k] = w;
                }
            #pragma unroll
            for (int tt = 0; tt < 2; ++tt)
                #pragma unroll
                for (int k = 0; k < 8; ++k)
                    Xw[tt][k] = __shfl_xor((int)Wd[tt][k], 32);

            // ---- PV (V already in registers)
            #pragma unroll
            for (int ks = 0; ks < 4; ++ks) {
                const int t2 = ks >> 1, bse = (ks & 1) * 4;
                unsigned w0 = hi ? Xw[t2][bse + 2] : Wd[t2][bse + 0];
                unsigned w1 = hi ? Xw[t2][bse + 3] : Wd[t2][bse + 1];
                unsigned w2 = hi ? Wd[t2][bse + 2] : Xw[t2][bse + 0];
                unsigned w3 = hi ? Wd[t2][bse + 3] : Xw[t2][bse + 1];
                unsigned pw4[4] = {w0, w1, w2, w3};
                bf16x8 pf = *(const bf16x8*)pw4;
                __builtin_amdgcn_s_setprio(1);
                #pragma unroll
                for (int dt = 0; dt < 2; ++dt)
                    o[dt] = mfma32(pf, vf[ks][dt], o[dt]);
                __builtin_amdgcn_s_setprio(0);
            }
        }
        END_BARRIER();
    }

    // ---- merge the two KV halves (oml aliased over dead bufs), store q-tile
    if (group == 1) {
        float* pp = oml + (size_t)(wq * 64 + lane) * 36;
        #pragma unroll
        for (int r = 0; r < 16; ++r) { pp[r] = o[0][r]; pp[16 + r] = o[1][r]; }
        pp[32] = m_run; pp[33] = l_run;
    }
    __syncthreads();
    if (group == 0) {
        const float* pp = oml + (size_t)(wq * 64 + lane) * 36;
        float m1 = pp[32], l1 = pp[33];
        float mn = fmaxf(m_run, m1);
        float a0 = __builtin_amdgcn_exp2f(m_run - mn);
        float a1 = __builtin_amdgcn_exp2f(m1 - mn);
        float lt = l_run * a0 + l1 * a1;
        float invl = 1.0f / lt;
        #pragma unroll
        for (int r = 0; r < 16; ++r) {
            int qsrc = (r & 3) + 8 * (r >> 2) + 4 * hi;
            float f0 = __shfl(a0, qsrc);
            float f1 = __shfl(a1, qsrc);
            float iv = __shfl(invl, qsrc);
            float v0 = (o[0][r] * f0 + pp[r] * f1) * iv;
            float v1 = (o[1][r] * f0 + pp[16 + r] * f1) * iv;
            int q = qrw + qsrc;
            size_t rowoff = ((size_t)(b_ * 2048 + q)) * 1024 + h_ * 64;
            yb[rowoff + l31]      = f2bf(v0);
            yb[rowoff + 32 + l31] = f2bf(v1);
        }
    }
}

extern "C" void kernel_launch(void* const* d_in, const int* in_sizes, int n_in,
                              void* d_out, int out_size, void* d_ws, size_t ws_size,
                              hipStream_t stream)
{
    const size_t MD = 4096ull * 1024;
    const size_t WD = 1024ull * 1024;
    ushort* ws  = (ushort*)d_ws;
    ushort* Qb  = ws;
    ushort* Kb  = Qb + MD;
    ushort* Vb  = Kb + MD;
    ushort* qhb = Vb + MD;
    ushort* khb = qhb + MD;
    ushort* vhT = khb + MD;
    ushort* WQb = vhT + MD;
    ushort* WKb = WQb + WD;
    ushort* WVb = WKb + WD;
    ushort* Wfb = WVb + WD;
    ushort* yb  = Qb;   // alias: Qb dead after QKV projection

    cvt7_kernel<<<dim3(4096, 7), 256, 0, stream>>>(
        (const float*)d_in[0], (const float*)d_in[1], (const float*)d_in[2],
        (const float*)d_in[3], (const float*)d_in[4], (const float*)d_in[5],
        (const float*)d_in[6],
        Qb, Kb, Vb, WQb, WKb, WVb, Wfb);

    gemm_qkv<<<dim3(96, 8), 256, 0, stream>>>(Qb, Kb, Vb, WQb, WKb, WVb, qhb, khb, vhT);
    attn_kernel<<<512, 512, 0, stream>>>(qhb, khb, vhT, yb);
    gemm_fc<<<dim3(32, 8), 256, 0, stream>>>(yb, Wfb, (float*)d_out, (const float*)d_in[7]);
}